// Round 8
// baseline (209.970 us; speedup 1.0000x reference)
//
#include <hip/hip_runtime.h>

#define DIM 1024
#define NHEADS 16
#define DH 64
#define BATCH 2
#define SEQ 2048

typedef float f32x4 __attribute__((ext_vector_type(4)));
typedef short s16x8 __attribute__((ext_vector_type(8)));
typedef short s16x4 __attribute__((ext_vector_type(4)));

__device__ __forceinline__ short f2bf(float f) {
    union { float f; unsigned u; } v; v.f = f;
    unsigned r = v.u + 0x7fffu + ((v.u >> 16) & 1u);   // RNE to bf16
    return (short)(r >> 16);
}

#if defined(__has_builtin)
#if __has_builtin(__builtin_amdgcn_cvt_pk_bf16_f32)
#define HAVE_PK_BF16 1
#endif
#endif
__device__ __forceinline__ unsigned f2bf_pk(float a, float b) {
#ifdef HAVE_PK_BF16
    typedef __bf16 bf16x2_t __attribute__((ext_vector_type(2)));
    bf16x2_t r = __builtin_amdgcn_cvt_pk_bf16_f32(a, b);
    return __builtin_bit_cast(unsigned, r);
#else
    return ((unsigned)(unsigned short)f2bf(b) << 16) | (unsigned short)f2bf(a);
#endif
}
__device__ __forceinline__ s16x4 pk4(float a, float b, float c, float d) {
    union { unsigned u[2]; s16x4 v; } x;
    x.u[0] = f2bf_pk(a, b); x.u[1] = f2bf_pk(c, d);
    return x.v;
}

#if defined(__has_builtin)
#if __has_builtin(__builtin_amdgcn_exp2f)
#define EXP2(x) __builtin_amdgcn_exp2f(x)
#endif
#endif
#ifndef EXP2
#define EXP2(x) exp2f(x)
#endif

// 16x16x16 bf16 MFMA (K=16): B-operand layout == C-layout of a 16x16 score tile,
// enabling direct register chaining QK^T -> softmax -> PV with no LDS round-trip.
#if defined(__has_builtin)
#if __has_builtin(__builtin_amdgcn_mfma_f32_16x16x16bf16_1k)
#define MFMA16(a, b, c) __builtin_amdgcn_mfma_f32_16x16x16bf16_1k(a, b, c, 0, 0, 0)
#elif __has_builtin(__builtin_amdgcn_mfma_f32_16x16x16_bf16)
#define MFMA16(a, b, c) __builtin_amdgcn_mfma_f32_16x16x16_bf16(a, b, c, 0, 0, 0)
#endif
#endif
#ifndef MFMA16
__device__ __forceinline__ f32x4 mfma16_asm(s16x4 a, s16x4 b, f32x4 c) {
    f32x4 d;
    asm volatile("v_mfma_f32_16x16x16_bf16 %0, %1, %2, %3"
                 : "=v"(d) : "v"(a), "v"(b), "0"(c));
    return d;
}
#define MFMA16(a, b, c) mfma16_asm(a, b, c)
#endif

// async global->LDS, 16 B per lane (GEMM staging)
__device__ __forceinline__ void gld16(const void* g, void* l) {
    __builtin_amdgcn_global_load_lds(
        (const __attribute__((address_space(1))) void*)g,
        (__attribute__((address_space(3))) void*)l, 16, 0, 0);
}

// ---------------- fused preproc: q -> bf16  AND  weights -> WT[4096][1024] bf16 ----------------
__global__ __launch_bounds__(256) void preproc_kernel(
    const float* __restrict__ q, short* __restrict__ qb,
    const float* __restrict__ Wq, const float* __restrict__ Wkv,
    const float* __restrict__ Wo, short* __restrict__ WT)
{
    const int bid = blockIdx.x;
    const int t = threadIdx.x;
    if (bid < 2048) {
        const int i = (bid * 256 + t) * 8;
        float4 a = *(const float4*)(q + i);
        float4 b = *(const float4*)(q + i + 4);
        union { unsigned u[4]; s16x8 v; } o;
        o.u[0] = f2bf_pk(a.x, a.y); o.u[1] = f2bf_pk(a.z, a.w);
        o.u[2] = f2bf_pk(b.x, b.y); o.u[3] = f2bf_pk(b.z, b.w);
        *(s16x8*)(qb + i) = o.v;
    } else {
        const int tb = bid - 2048;
        const int ng = (tb & 63) * 64 + (t & 63);            // 0..4095
        const int k0 = ((tb >> 6) * 4 + (t >> 6)) * 8;
        const float* W; int n, N;
        if (ng < 1024)      { W = Wq;  n = ng;        N = 1024; }
        else if (ng < 3072) { W = Wkv; n = ng - 1024; N = 2048; }
        else                { W = Wo;  n = ng - 3072; N = 1024; }
        float v[8];
#pragma unroll
        for (int j = 0; j < 8; ++j) v[j] = W[(size_t)(k0 + j) * N + n];
        union { unsigned u[4]; s16x8 s; } o;
        o.u[0] = f2bf_pk(v[0], v[1]); o.u[1] = f2bf_pk(v[2], v[3]);
        o.u[2] = f2bf_pk(v[4], v[5]); o.u[3] = f2bf_pk(v[6], v[7]);
        *(s16x8*)&WT[(size_t)ng * 1024 + k0] = o.s;
    }
}

// ---------------- bf16 MFMA GEMM with fused V-transpose epilogue ----------------
template<int TM, bool OUT_BF16>
__global__ __launch_bounds__(256) void gemm_mfma_kernel(
    const short* __restrict__ A, const short* __restrict__ Bt,
    const float* __restrict__ bias0, const float* __restrict__ bias1, int nsplit,
    float s0, float s1, void* __restrict__ C, short* __restrict__ VtG, int vt_split,
    int M, int N)
{
    const int K = 1024;
    constexpr int NI = (TM == 128) ? 4 : 2;
    __shared__ short As[TM * 32];
    __shared__ short Bs[128 * 32];

    const int t    = threadIdx.x;
    const int wave = t >> 6;
    const int lane = t & 63;
    const int col  = lane & 15;
    const int quad = lane >> 4;
    const int m0 = blockIdx.y * TM;
    const int n0 = blockIdx.x * 128;
    const int wroff = (TM == 128) ? (wave >> 1) * 64 : 0;
    const int wcoff = (TM == 128) ? (wave & 1) * 64 : wave * 32;

    f32x4 acc[4][NI];
#pragma unroll
    for (int mi = 0; mi < 4; ++mi)
#pragma unroll
        for (int ni = 0; ni < NI; ++ni) acc[mi][ni] = (f32x4){0.f, 0.f, 0.f, 0.f};

    constexpr int RPW = TM / 4;
    const int ldrowA = wave * RPW + (lane >> 2);
    const int ldrowB = wave * 32  + (lane >> 2);
    const int ldcol  = (lane & 3) * 8;
    const short* Ag = A  + (size_t)(m0 + ldrowA) * K + ldcol;
    const short* Bg = Bt + (size_t)(n0 + ldrowB) * K + ldcol;
    short* AsW = &As[wave * RPW * 32];
    short* BsW = &Bs[wave * 1024];

    for (int k0 = 0; k0 < K; k0 += 32) {
        __syncthreads();
        gld16(Ag + k0, AsW);
        if (TM == 128) gld16(Ag + 16 * K + k0, AsW + 512);
        gld16(Bg + k0,          BsW);
        gld16(Bg + 16 * K + k0, BsW + 512);
        __syncthreads();

        s16x8 aA[4], bB[NI];
#pragma unroll
        for (int mi = 0; mi < 4; ++mi)
            aA[mi] = *(const s16x8*)&As[(wroff + 16 * mi + col) * 32 + quad * 8];
#pragma unroll
        for (int ni = 0; ni < NI; ++ni)
            bB[ni] = *(const s16x8*)&Bs[(wcoff + 16 * ni + col) * 32 + quad * 8];
#pragma unroll
        for (int mi = 0; mi < 4; ++mi)
#pragma unroll
            for (int ni = 0; ni < NI; ++ni)
                acc[mi][ni] = __builtin_amdgcn_mfma_f32_16x16x32_bf16(aA[mi], bB[ni], acc[mi][ni], 0, 0, 0);
    }

    float bias_v[NI], scale_v[NI];
#pragma unroll
    for (int ni = 0; ni < NI; ++ni) {
        int nb = n0 + wcoff + 16 * ni + col;
        bias_v[ni]  = (nb < nsplit) ? bias0[nb] : bias1[nb - nsplit];
        scale_v[ni] = (nb < nsplit) ? s0 : s1;
    }

    if (vt_split >= 0 && n0 >= vt_split) {
        // V tile: write transposed to VtG; lane holds 4 consecutive tokens per (mi,ni)
#pragma unroll
        for (int mi = 0; mi < 4; ++mi)
#pragma unroll
            for (int ni = 0; ni < NI; ++ni) {
                const int gm = m0 + wroff + 16 * mi + quad * 4;       // token base
                const int gn = n0 + wcoff + 16 * ni + col;            // V column
                const int hv = (gn - vt_split) >> 6;
                const int dv = (gn - vt_split) & 63;
                const int bb = gm >> 11, tok = gm & 2047;
                f32x4 v;
#pragma unroll
                for (int r = 0; r < 4; ++r) v[r] = (acc[mi][ni][r] + bias_v[ni]) * scale_v[ni];
                *(s16x4*)(VtG + (size_t)((bb * NHEADS + hv) * 64 + dv) * SEQ + tok) =
                    pk4(v[0], v[1], v[2], v[3]);
            }
    } else {
#pragma unroll
        for (int mi = 0; mi < 4; ++mi)
#pragma unroll
            for (int ni = 0; ni < NI; ++ni)
#pragma unroll
                for (int r = 0; r < 4; ++r) {
                    const int gm = m0 + wroff + 16 * mi + quad * 4 + r;
                    const int gn = n0 + wcoff + 16 * ni + col;
                    float v = (acc[mi][ni][r] + bias_v[ni]) * scale_v[ni];
                    if (OUT_BF16) ((short*)C)[(size_t)gm * N + gn] = f2bf(v);
                    else          ((float*)C)[(size_t)gm * N + gn] = v;
                }
    }
}

// ---------------- MFMA flash attention v7: direct-register PV ----------------
// Block = (256-q tile, head, batch), 512 threads / 8 waves (4 q-quarters x 2 key-halves).
// QK^T via 16x16x32 (aK from LDS); P = exp2(S^T) packed in-register IS the B-frag of
// 16x16x16 MFMA (C-layout == B-layout for K=16) -> PV with zero LDS traffic for P.
__global__ __launch_bounds__(512) void attn_v7_kernel(
    const short* __restrict__ QKV,  // [B*S, 3072] bf16 (Q pre-scaled by 0.125*log2e)
    const short* __restrict__ VtG,  // [(b*NH+h)*64+dv][SEQ] bf16
    short* __restrict__ O)          // [B*S, 1024] bf16
{
    const int qt = blockIdx.x;      // 0..7
    const int h  = blockIdx.y;
    const int b  = blockIdx.z;
    const int t  = threadIdx.x;
    const int wave = t >> 6;
    const int lane = t & 63;
    const int col  = lane & 15;
    const int quad = lane >> 4;
    const int wq = wave & 3;        // q-quarter
    const int kh = wave >> 2;       // key half

    // 72 KB: Ks buffers at [cur*4608], Vt at [9216 + cur*4608]; aliased for merge scratch
    __shared__ short smem[4 * 64 * 72];

    const short* Qg = QKV + (size_t)(b * SEQ + qt * 256) * 3072 + h * DH;
    const short* Kg = QKV + (size_t)(b * SEQ) * 3072 + 1024 + h * DH;
    const short* VtRow = VtG + (size_t)(b * NHEADS + h) * 64 * SEQ;

    // Q B-frags straight from global
    s16x8 aQ[4][2];
#pragma unroll
    for (int tq = 0; tq < 4; ++tq)
#pragma unroll
        for (int kq = 0; kq < 2; ++kq)
            aQ[tq][kq] = *(const s16x8*)(Qg + (size_t)(wq * 64 + 16 * tq + col) * 3072 + kq * 32 + quad * 8);

    f32x4 oa[4][4];                 // [td][tq] : O^T[dv][q] partial (this key half)
    float lsum[4] = {0.f, 0.f, 0.f, 0.f};
#pragma unroll
    for (int td = 0; td < 4; ++td)
#pragma unroll
        for (int tq = 0; tq < 4; ++tq) oa[td][tq] = (f32x4){0.f, 0.f, 0.f, 0.f};

    // stagers: 512 threads; 1 b128 each covers a 64x64 bf16 tile
    const int srow = t >> 3;         // 0..63
    const int sc8  = (t & 7) * 8;
    const short* KgS  = Kg + (size_t)srow * 3072 + sc8;
    const short* VtgS = VtRow + (size_t)srow * SEQ + sc8;
    s16x8 kx = *(const s16x8*)KgS;
    s16x8 vx = *(const s16x8*)VtgS;

    for (int kt = 0; kt < SEQ / 64; ++kt) {
        const int curK = (kt & 1) * 4608;
        const int curV = 9216 + (kt & 1) * 4608;
        *(s16x8*)&smem[curK + srow * 72 + sc8] = kx;
        *(s16x8*)&smem[curV + srow * 72 + sc8] = vx;
        {   // prefetch next tile into regs (clamped)
            int nt = (kt + 1 < SEQ / 64) ? kt + 1 : kt;
            kx = *(const s16x8*)(KgS + (size_t)nt * 64 * 3072);
            vx = *(const s16x8*)(VtgS + (size_t)nt * 64);
        }
        __syncthreads();   // double-buffered: single barrier per iter

        // S^T[key(32 of this half)][q(64)] = K . Q^T   (pre-scaled by 0.125*log2e)
        s16x8 aK[2][2];
#pragma unroll
        for (int tk = 0; tk < 2; ++tk)
#pragma unroll
            for (int kq = 0; kq < 2; ++kq)
                aK[tk][kq] = *(const s16x8*)&smem[curK + (kh * 32 + 16 * tk + col) * 72 + kq * 32 + quad * 8];

        s16x4 bP[2][4];
#pragma unroll
        for (int tk = 0; tk < 2; ++tk)
#pragma unroll
            for (int tq = 0; tq < 4; ++tq) {
                f32x4 a = (f32x4){0.f, 0.f, 0.f, 0.f};
                a = __builtin_amdgcn_mfma_f32_16x16x32_bf16(aK[tk][0], aQ[tq][0], a, 0, 0, 0);
                a = __builtin_amdgcn_mfma_f32_16x16x32_bf16(aK[tk][1], aQ[tq][1], a, 0, 0, 0);
                float p0 = EXP2(a[0]);
                float p1 = EXP2(a[1]);
                float p2 = EXP2(a[2]);
                float p3 = EXP2(a[3]);
                lsum[tq] += (p0 + p1) + (p2 + p3);
                bP[tk][tq] = pk4(p0, p1, p2, p3);   // == B-frag of 16x16x16 MFMA
            }

        // O^T += V^T . P  — A-frag: Vt[dv][16*tk + quad*4 ..+3] (b64), B-frag: bP regs
#pragma unroll
        for (int td = 0; td < 4; ++td) {
            const int dv = 16 * td + col;
#pragma unroll
            for (int tk = 0; tk < 2; ++tk) {
                s16x4 aV = *(const s16x4*)&smem[curV + dv * 72 + kh * 32 + 16 * tk + quad * 4];
#pragma unroll
                for (int tq = 0; tq < 4; ++tq)
                    oa[td][tq] = MFMA16(aV, bP[tk][tq], oa[td][tq]);
            }
        }
    }

    // reduce lsum over quads (keys spread across quads)
#pragma unroll
    for (int tq = 0; tq < 4; ++tq) {
        lsum[tq] += __shfl_xor(lsum[tq], 16);
        lsum[tq] += __shfl_xor(lsum[tq], 32);
    }

    // cross-wave (key-half) fp32 merge via LDS (aliases smem), 2 rounds of 2 pairs
    __syncthreads();
    float* red  = (float*)smem;        // 2 slots x 4096 floats = 32 KB
    float* redl = red + 8192;          // 2 slots x 64 floats
#pragma unroll
    for (int round = 0; round < 2; ++round) {
        if (wave >= 4 && ((wave >> 1) & 1) == round) {
            const int slot = wave & 1;
#pragma unroll
            for (int td = 0; td < 4; ++td)
#pragma unroll
                for (int tq = 0; tq < 4; ++tq)
#pragma unroll
                    for (int r = 0; r < 4; ++r)
                        red[slot * 4096 + (16 * td + quad * 4 + r) * 64 + 16 * tq + col] = oa[td][tq][r];
            if (quad == 0)
#pragma unroll
                for (int tq = 0; tq < 4; ++tq)
                    redl[slot * 64 + 16 * tq + col] = lsum[tq];
        }
        __syncthreads();
        if (wave < 4 && ((wave >> 1) & 1) == round) {
            const int slot = wave & 1;
#pragma unroll
            for (int td = 0; td < 4; ++td)
#pragma unroll
                for (int tq = 0; tq < 4; ++tq)
#pragma unroll
                    for (int r = 0; r < 4; ++r)
                        oa[td][tq][r] += red[slot * 4096 + (16 * td + quad * 4 + r) * 64 + 16 * tq + col];
#pragma unroll
            for (int tq = 0; tq < 4; ++tq)
                lsum[tq] += redl[slot * 64 + 16 * tq + col];
        }
        __syncthreads();
    }

    // normalize + write (waves 0..3 only)
    if (wave < 4) {
        short* Og = O + (size_t)(b * SEQ + qt * 256 + wq * 64) * DIM + h * DH;
        float inv[4];
#pragma unroll
        for (int tq = 0; tq < 4; ++tq) inv[tq] = 1.f / lsum[tq];
#pragma unroll
        for (int td = 0; td < 4; ++td)
#pragma unroll
            for (int tq = 0; tq < 4; ++tq)
                *(s16x4*)(Og + (size_t)(16 * tq + col) * DIM + 16 * td + quad * 4) =
                    pk4(oa[td][tq][0] * inv[tq], oa[td][tq][1] * inv[tq],
                        oa[td][tq][2] * inv[tq], oa[td][tq][3] * inv[tq]);
    }
}

extern "C" void kernel_launch(void* const* d_in, const int* in_sizes, int n_in,
                              void* d_out, int out_size, void* d_ws, size_t ws_size,
                              hipStream_t stream)
{
    const float* q   = (const float*)d_in[0];
    const float* Wq  = (const float*)d_in[1];
    const float* bq  = (const float*)d_in[2];
    const float* Wkv = (const float*)d_in[3];
    const float* bkv = (const float*)d_in[4];
    const float* Wo  = (const float*)d_in[5];
    const float* bo  = (const float*)d_in[6];
    float* out = (float*)d_out;

    const int M = BATCH * SEQ;   // 4096

    // ws (48 MB): qb 8 | WT 8 | QKV 24 | AO 8.  VtG (8 MB) lives in d_out (dead until out-GEMM).
    short* qb     = (short*)d_ws;
    short* WT     = qb     + (size_t)M * DIM;             // [4096][1024]: Wq|Wkv|Wo transposed
    short* QKVbuf = WT     + (size_t)4096 * DIM;
    short* AObuf  = QKVbuf + (size_t)M * 3 * DIM;
    short* VtG    = (short*)d_out;

    const float QSCALE = 0.18033688011112042f;   // 0.125 * log2(e)

    preproc_kernel<<<4096, 256, 0, stream>>>(q, qb, Wq, Wkv, Wo, WT);

    // fused QKV projection; V tiles (n0 >= 2048) stream transposed into VtG
    gemm_mfma_kernel<128, true><<<dim3(3 * DIM / 128, M / 128), 256, 0, stream>>>(
        qb, WT, bq, bkv, DIM, QSCALE, 1.0f, QKVbuf, VtG, 2048, M, 3 * DIM);
    attn_v7_kernel<<<dim3(SEQ / 256, NHEADS, BATCH), 512, 0, stream>>>(QKVbuf, VtG, AObuf);
    gemm_mfma_kernel<64, false><<<dim3(DIM / 128, M / 64), 256, 0, stream>>>(
        AObuf, WT + (size_t)3072 * 1024, bo, bo, 1 << 30, 1.0f, 1.0f, out, nullptr, -1, M, DIM);
}

// Round 9
// 208.466 us; speedup vs baseline: 1.0072x; 1.0072x over previous
//
#include <hip/hip_runtime.h>

#define DIM 1024
#define NHEADS 16
#define DH 64
#define BATCH 2
#define SEQ 2048

typedef float f32x4 __attribute__((ext_vector_type(4)));
typedef short s16x8 __attribute__((ext_vector_type(8)));
typedef short s16x4 __attribute__((ext_vector_type(4)));

__device__ __forceinline__ short f2bf(float f) {
    union { float f; unsigned u; } v; v.f = f;
    unsigned r = v.u + 0x7fffu + ((v.u >> 16) & 1u);   // RNE to bf16
    return (short)(r >> 16);
}

#if defined(__has_builtin)
#if __has_builtin(__builtin_amdgcn_cvt_pk_bf16_f32)
#define HAVE_PK_BF16 1
#endif
#endif
__device__ __forceinline__ unsigned f2bf_pk(float a, float b) {
#ifdef HAVE_PK_BF16
    typedef __bf16 bf16x2_t __attribute__((ext_vector_type(2)));
    bf16x2_t r = __builtin_amdgcn_cvt_pk_bf16_f32(a, b);
    return __builtin_bit_cast(unsigned, r);
#else
    return ((unsigned)(unsigned short)f2bf(b) << 16) | (unsigned short)f2bf(a);
#endif
}
__device__ __forceinline__ s16x4 pk4(float a, float b, float c, float d) {
    union { unsigned u[2]; s16x4 v; } x;
    x.u[0] = f2bf_pk(a, b); x.u[1] = f2bf_pk(c, d);
    return x.v;
}

#if defined(__has_builtin)
#if __has_builtin(__builtin_amdgcn_exp2f)
#define EXP2(x) __builtin_amdgcn_exp2f(x)
#endif
#endif
#ifndef EXP2
#define EXP2(x) exp2f(x)
#endif

// 16x16x16 bf16 MFMA: B-operand layout == C-layout of a 16x16 score tile (K=16),
// so exp2(scores) packed in-register feeds PV directly (no P LDS round-trip).
#if defined(__has_builtin)
#if __has_builtin(__builtin_amdgcn_mfma_f32_16x16x16bf16_1k)
#define MFMA16(a, b, c) __builtin_amdgcn_mfma_f32_16x16x16bf16_1k(a, b, c, 0, 0, 0)
#elif __has_builtin(__builtin_amdgcn_mfma_f32_16x16x16_bf16)
#define MFMA16(a, b, c) __builtin_amdgcn_mfma_f32_16x16x16_bf16(a, b, c, 0, 0, 0)
#endif
#endif
#ifndef MFMA16
__device__ __forceinline__ f32x4 mfma16_asm(s16x4 a, s16x4 b, f32x4 c) {
    f32x4 d;
    asm volatile("v_mfma_f32_16x16x16_bf16 %0, %1, %2, %3"
                 : "=v"(d) : "v"(a), "v"(b), "0"(c));
    return d;
}
#define MFMA16(a, b, c) mfma16_asm(a, b, c)
#endif

// async global->LDS, 16 B per lane (GEMM staging)
__device__ __forceinline__ void gld16(const void* g, void* l) {
    __builtin_amdgcn_global_load_lds(
        (const __attribute__((address_space(1))) void*)g,
        (__attribute__((address_space(3))) void*)l, 16, 0, 0);
}

// ---------------- fused preproc: q -> bf16  AND  weights -> WT[4096][1024] bf16 ----------------
__global__ __launch_bounds__(256) void preproc_kernel(
    const float* __restrict__ q, short* __restrict__ qb,
    const float* __restrict__ Wq, const float* __restrict__ Wkv,
    const float* __restrict__ Wo, short* __restrict__ WT)
{
    const int bid = blockIdx.x;
    const int t = threadIdx.x;
    if (bid < 2048) {
        const int i = (bid * 256 + t) * 8;
        float4 a = *(const float4*)(q + i);
        float4 b = *(const float4*)(q + i + 4);
        union { unsigned u[4]; s16x8 v; } o;
        o.u[0] = f2bf_pk(a.x, a.y); o.u[1] = f2bf_pk(a.z, a.w);
        o.u[2] = f2bf_pk(b.x, b.y); o.u[3] = f2bf_pk(b.z, b.w);
        *(s16x8*)(qb + i) = o.v;
    } else {
        const int tb = bid - 2048;
        const int ng = (tb & 63) * 64 + (t & 63);            // 0..4095
        const int k0 = ((tb >> 6) * 4 + (t >> 6)) * 8;
        const float* W; int n, N;
        if (ng < 1024)      { W = Wq;  n = ng;        N = 1024; }
        else if (ng < 3072) { W = Wkv; n = ng - 1024; N = 2048; }
        else                { W = Wo;  n = ng - 3072; N = 1024; }
        float v[8];
#pragma unroll
        for (int j = 0; j < 8; ++j) v[j] = W[(size_t)(k0 + j) * N + n];
        union { unsigned u[4]; s16x8 s; } o;
        o.u[0] = f2bf_pk(v[0], v[1]); o.u[1] = f2bf_pk(v[2], v[3]);
        o.u[2] = f2bf_pk(v[4], v[5]); o.u[3] = f2bf_pk(v[6], v[7]);
        *(s16x8*)&WT[(size_t)ng * 1024 + k0] = o.s;
    }
}

// ---------------- V part of QKV -> VtG[(b*NH+h)*64+dv][SEQ] (coalesced) ----------------
__global__ __launch_bounds__(256) void transpose_v_kernel(
    const short* __restrict__ QKV, short* __restrict__ VtG)
{
    const int t = threadIdx.x;
    const int tok0 = blockIdx.x * 64;
    const int h = blockIdx.y, b = blockIdx.z;
    __shared__ short L[64 * 72];
    const short* src = QKV + (size_t)(b * SEQ + tok0) * 3072 + 2048 + h * 64;
#pragma unroll
    for (int p = 0; p < 2; ++p) {
        int r = p * 32 + (t >> 3);
        *(s16x8*)&L[r * 72 + (t & 7) * 8] = *(const s16x8*)(src + (size_t)r * 3072 + (t & 7) * 8);
    }
    __syncthreads();
    short* dst = VtG + (size_t)(b * NHEADS + h) * 64 * SEQ + tok0;
#pragma unroll
    for (int p = 0; p < 2; ++p) {
        int u = p * 256 + t;
        int dv = u >> 3, c = (u & 7) * 8;
        s16x8 o;
#pragma unroll
        for (int j = 0; j < 8; ++j) o[j] = L[(c + j) * 72 + dv];
        *(s16x8*)(dst + (size_t)dv * SEQ + c) = o;
    }
}

// ---------------- bf16 MFMA GEMM: C = A @ Bt^T, epilogue (acc+bias)*scale ----------------
template<int TM, bool OUT_BF16>
__global__ __launch_bounds__(256) void gemm_mfma_kernel(
    const short* __restrict__ A, const short* __restrict__ Bt,
    const float* __restrict__ bias0, const float* __restrict__ bias1, int nsplit,
    float s0, float s1, void* __restrict__ C, int M, int N)
{
    const int K = 1024;
    constexpr int NI = (TM == 128) ? 4 : 2;
    __shared__ short As[TM * 32];
    __shared__ short Bs[128 * 32];

    const int t    = threadIdx.x;
    const int wave = t >> 6;
    const int lane = t & 63;
    const int col  = lane & 15;
    const int quad = lane >> 4;
    const int m0 = blockIdx.y * TM;
    const int n0 = blockIdx.x * 128;
    const int wroff = (TM == 128) ? (wave >> 1) * 64 : 0;
    const int wcoff = (TM == 128) ? (wave & 1) * 64 : wave * 32;

    f32x4 acc[4][NI];
#pragma unroll
    for (int mi = 0; mi < 4; ++mi)
#pragma unroll
        for (int ni = 0; ni < NI; ++ni) acc[mi][ni] = (f32x4){0.f, 0.f, 0.f, 0.f};

    constexpr int RPW = TM / 4;
    const int ldrowA = wave * RPW + (lane >> 2);
    const int ldrowB = wave * 32  + (lane >> 2);
    const int ldcol  = (lane & 3) * 8;
    const short* Ag = A  + (size_t)(m0 + ldrowA) * K + ldcol;
    const short* Bg = Bt + (size_t)(n0 + ldrowB) * K + ldcol;
    short* AsW = &As[wave * RPW * 32];
    short* BsW = &Bs[wave * 1024];

    for (int k0 = 0; k0 < K; k0 += 32) {
        __syncthreads();
        gld16(Ag + k0, AsW);
        if (TM == 128) gld16(Ag + 16 * K + k0, AsW + 512);
        gld16(Bg + k0,          BsW);
        gld16(Bg + 16 * K + k0, BsW + 512);
        __syncthreads();

        s16x8 aA[4], bB[NI];
#pragma unroll
        for (int mi = 0; mi < 4; ++mi)
            aA[mi] = *(const s16x8*)&As[(wroff + 16 * mi + col) * 32 + quad * 8];
#pragma unroll
        for (int ni = 0; ni < NI; ++ni)
            bB[ni] = *(const s16x8*)&Bs[(wcoff + 16 * ni + col) * 32 + quad * 8];
#pragma unroll
        for (int mi = 0; mi < 4; ++mi)
#pragma unroll
            for (int ni = 0; ni < NI; ++ni)
                acc[mi][ni] = __builtin_amdgcn_mfma_f32_16x16x32_bf16(aA[mi], bB[ni], acc[mi][ni], 0, 0, 0);
    }

    float bias_v[NI], scale_v[NI];
#pragma unroll
    for (int ni = 0; ni < NI; ++ni) {
        int nb = n0 + wcoff + 16 * ni + col;
        bias_v[ni]  = (nb < nsplit) ? bias0[nb] : bias1[nb - nsplit];
        scale_v[ni] = (nb < nsplit) ? s0 : s1;
    }

#pragma unroll
    for (int mi = 0; mi < 4; ++mi)
#pragma unroll
        for (int ni = 0; ni < NI; ++ni)
#pragma unroll
            for (int r = 0; r < 4; ++r) {
                const int gm = m0 + wroff + 16 * mi + quad * 4 + r;
                const int gn = n0 + wcoff + 16 * ni + col;
                float v = (acc[mi][ni][r] + bias_v[ni]) * scale_v[ni];
                if (OUT_BF16) ((short*)C)[(size_t)gm * N + gn] = f2bf(v);
                else          ((float*)C)[(size_t)gm * N + gn] = v;
            }
}

// ---------------- MFMA flash attention v8: BK=128, direct-register PV ----------------
// Block = (256-q tile, head, batch), 512 threads / 8 waves (4 q-quarters x 2 key-halves).
// 16 iterations of 128 keys (double-buffered, 1 barrier/iter) — halves barrier-stall count
// vs BK=64. QK^T via 16x16x32; P = exp2(S^T) in-register IS the 16x16x16 B-frag -> PV
// with zero LDS P traffic.
__global__ __launch_bounds__(512) void attn_v8_kernel(
    const short* __restrict__ QKV,  // [B*S, 3072] bf16 (Q pre-scaled by 0.125*log2e)
    const short* __restrict__ VtG,  // [(b*NH+h)*64+dv][SEQ] bf16
    short* __restrict__ O)          // [B*S, 1024] bf16
{
    const int qt = blockIdx.x;      // 0..7
    const int h  = blockIdx.y;
    const int b  = blockIdx.z;
    const int t  = threadIdx.x;
    const int wave = t >> 6;
    const int lane = t & 63;
    const int col  = lane & 15;
    const int quad = lane >> 4;
    const int wq = wave & 3;        // q-quarter (64 q rows)
    const int kh = wave >> 2;       // key half (64 of 128 keys per iter)

    // shorts: Ks[2] @ {0, 9216} (128 rows x 72), Vt[2] @ 18432 + {0, 8704} (64 dv x 136)
    // total 35840 shorts = 70 KB; merge scratch (33280 shorts) aliases after the loop
    __shared__ short smem[35840];

    const short* Qg = QKV + (size_t)(b * SEQ + qt * 256) * 3072 + h * DH;
    const short* Kg = QKV + (size_t)(b * SEQ) * 3072 + 1024 + h * DH;
    const short* VtRow = VtG + (size_t)(b * NHEADS + h) * 64 * SEQ;

    // Q B-frags straight from global
    s16x8 aQ[4][2];
#pragma unroll
    for (int tq = 0; tq < 4; ++tq)
#pragma unroll
        for (int kq = 0; kq < 2; ++kq)
            aQ[tq][kq] = *(const s16x8*)(Qg + (size_t)(wq * 64 + 16 * tq + col) * 3072 + kq * 32 + quad * 8);

    f32x4 oa[4][4];                 // [td][tq] : O^T[dv][q] partial (this key half)
    float lsum[4] = {0.f, 0.f, 0.f, 0.f};
#pragma unroll
    for (int td = 0; td < 4; ++td)
#pragma unroll
        for (int tq = 0; tq < 4; ++tq) oa[td][tq] = (f32x4){0.f, 0.f, 0.f, 0.f};

    // stagers (512 threads): K tile = 128 rows x 64 d; Vt tile = 64 dv x 128 tok
    const int srow = t >> 3;          // 0..63 (K rows srow, srow+64)
    const int sc8  = (t & 7) * 8;
    const int dvS  = t >> 4;          // 0..31 (Vt rows dvS, dvS+32)
    const int tokc = (t & 15) * 8;
    const short* KgS  = Kg + (size_t)srow * 3072 + sc8;
    const short* VtgS = VtRow + (size_t)dvS * SEQ + tokc;

    s16x8 kx[2], vx[2];
#pragma unroll
    for (int p = 0; p < 2; ++p) {
        kx[p] = *(const s16x8*)(KgS + (size_t)p * 64 * 3072);
        vx[p] = *(const s16x8*)(VtgS + (size_t)p * 32 * SEQ);
    }

    for (int kt = 0; kt < SEQ / 128; ++kt) {
        const int KsOff = (kt & 1) * 9216;
        const int VtOff = 18432 + (kt & 1) * 8704;
#pragma unroll
        for (int p = 0; p < 2; ++p) {
            *(s16x8*)&smem[KsOff + (srow + p * 64) * 72 + sc8] = kx[p];
            *(s16x8*)&smem[VtOff + (dvS + p * 32) * 136 + tokc] = vx[p];
        }
        {   // prefetch next tile into regs (clamped)
            int nt = (kt + 1 < SEQ / 128) ? kt + 1 : kt;
#pragma unroll
            for (int p = 0; p < 2; ++p) {
                kx[p] = *(const s16x8*)(KgS + (size_t)(nt * 128 + p * 64) * 3072);
                vx[p] = *(const s16x8*)(VtgS + (size_t)p * 32 * SEQ + nt * 128);
            }
        }
        __syncthreads();   // double-buffered: single barrier per iter

        // per 16-key slice tk: QK^T -> exp2 -> PV (4 independent chains for ILP)
#pragma unroll
        for (int tk = 0; tk < 4; ++tk) {
            const int krow = kh * 64 + 16 * tk + col;
            s16x8 aK0 = *(const s16x8*)&smem[KsOff + krow * 72 + quad * 8];
            s16x8 aK1 = *(const s16x8*)&smem[KsOff + krow * 72 + 32 + quad * 8];

            s16x4 bP[4];
#pragma unroll
            for (int tq = 0; tq < 4; ++tq) {
                f32x4 a = (f32x4){0.f, 0.f, 0.f, 0.f};
                a = __builtin_amdgcn_mfma_f32_16x16x32_bf16(aK0, aQ[tq][0], a, 0, 0, 0);
                a = __builtin_amdgcn_mfma_f32_16x16x32_bf16(aK1, aQ[tq][1], a, 0, 0, 0);
                float p0 = EXP2(a[0]);
                float p1 = EXP2(a[1]);
                float p2 = EXP2(a[2]);
                float p3 = EXP2(a[3]);
                lsum[tq] += (p0 + p1) + (p2 + p3);
                bP[tq] = pk4(p0, p1, p2, p3);   // == B-frag of 16x16x16 MFMA
            }
#pragma unroll
            for (int td = 0; td < 4; ++td) {
                s16x4 aV = *(const s16x4*)&smem[VtOff + (16 * td + col) * 136 + kh * 64 + 16 * tk + quad * 4];
#pragma unroll
                for (int tq = 0; tq < 4; ++tq)
                    oa[td][tq] = MFMA16(aV, bP[tq], oa[td][tq]);
            }
        }
    }

    // reduce lsum over quads (keys spread across quads)
#pragma unroll
    for (int tq = 0; tq < 4; ++tq) {
        lsum[tq] += __shfl_xor(lsum[tq], 16);
        lsum[tq] += __shfl_xor(lsum[tq], 32);
    }

    // cross-wave (key-half) fp32 merge via LDS (aliases smem), 2 rounds of 2 pairs
    __syncthreads();
    float* red  = (float*)smem;        // 2 slots x 4096 floats = 32 KB
    float* redl = red + 8192;          // 2 slots x 64 floats
#pragma unroll
    for (int round = 0; round < 2; ++round) {
        if (wave >= 4 && ((wave >> 1) & 1) == round) {
            const int slot = wave & 1;
#pragma unroll
            for (int td = 0; td < 4; ++td)
#pragma unroll
                for (int tq = 0; tq < 4; ++tq)
#pragma unroll
                    for (int r = 0; r < 4; ++r)
                        red[slot * 4096 + (16 * td + quad * 4 + r) * 64 + 16 * tq + col] = oa[td][tq][r];
            if (quad == 0)
#pragma unroll
                for (int tq = 0; tq < 4; ++tq)
                    redl[slot * 64 + 16 * tq + col] = lsum[tq];
        }
        __syncthreads();
        if (wave < 4 && ((wave >> 1) & 1) == round) {
            const int slot = wave & 1;
#pragma unroll
            for (int td = 0; td < 4; ++td)
#pragma unroll
                for (int tq = 0; tq < 4; ++tq)
#pragma unroll
                    for (int r = 0; r < 4; ++r)
                        oa[td][tq][r] += red[slot * 4096 + (16 * td + quad * 4 + r) * 64 + 16 * tq + col];
#pragma unroll
            for (int tq = 0; tq < 4; ++tq)
                lsum[tq] += redl[slot * 64 + 16 * tq + col];
        }
        __syncthreads();
    }

    // normalize + write (waves 0..3 only)
    if (wave < 4) {
        short* Og = O + (size_t)(b * SEQ + qt * 256 + wq * 64) * DIM + h * DH;
        float inv[4];
#pragma unroll
        for (int tq = 0; tq < 4; ++tq) inv[tq] = 1.f / lsum[tq];
#pragma unroll
        for (int td = 0; td < 4; ++td)
#pragma unroll
            for (int tq = 0; tq < 4; ++tq)
                *(s16x4*)(Og + (size_t)(16 * tq + col) * DIM + 16 * td + quad * 4) =
                    pk4(oa[td][tq][0] * inv[tq], oa[td][tq][1] * inv[tq],
                        oa[td][tq][2] * inv[tq], oa[td][tq][3] * inv[tq]);
    }
}

extern "C" void kernel_launch(void* const* d_in, const int* in_sizes, int n_in,
                              void* d_out, int out_size, void* d_ws, size_t ws_size,
                              hipStream_t stream)
{
    const float* q   = (const float*)d_in[0];
    const float* Wq  = (const float*)d_in[1];
    const float* bq  = (const float*)d_in[2];
    const float* Wkv = (const float*)d_in[3];
    const float* bkv = (const float*)d_in[4];
    const float* Wo  = (const float*)d_in[5];
    const float* bo  = (const float*)d_in[6];
    float* out = (float*)d_out;

    const int M = BATCH * SEQ;   // 4096

    // ws (48 MB): qb 8 | WT 8 | QKV 24 | AO 8.  VtG (8 MB) lives in d_out (dead until out-GEMM).
    short* qb     = (short*)d_ws;
    short* WT     = qb     + (size_t)M * DIM;             // [4096][1024]: Wq|Wkv|Wo transposed
    short* QKVbuf = WT     + (size_t)4096 * DIM;
    short* AObuf  = QKVbuf + (size_t)M * 3 * DIM;
    short* VtG    = (short*)d_out;

    const float QSCALE = 0.18033688011112042f;   // 0.125 * log2(e)

    preproc_kernel<<<4096, 256, 0, stream>>>(q, qb, Wq, Wkv, Wo, WT);

    // fused QKV projection (plain coalesced epilogue)
    gemm_mfma_kernel<128, true><<<dim3(3 * DIM / 128, M / 128), 256, 0, stream>>>(
        qb, WT, bq, bkv, DIM, QSCALE, 1.0f, QKVbuf, M, 3 * DIM);
    transpose_v_kernel<<<dim3(SEQ / 64, NHEADS, BATCH), 256, 0, stream>>>(QKVbuf, VtG);
    attn_v8_kernel<<<dim3(SEQ / 256, NHEADS, BATCH), 512, 0, stream>>>(QKVbuf, VtG, AObuf);
    gemm_mfma_kernel<64, false><<<dim3(DIM / 128, M / 64), 256, 0, stream>>>(
        AObuf, WT + (size_t)3072 * 1024, bo, bo, 1 << 30, 1.0f, 1.0f, out, M, DIM);
}